// Round 19
// baseline (96.782 us; speedup 1.0000x reference)
//
#include <hip/hip_runtime.h>
#include <hip/hip_bf16.h>
#include <cstdint>
#include <cstddef>

typedef __bf16 bf16x8 __attribute__((ext_vector_type(8)));
typedef __bf16 bf16x4 __attribute__((ext_vector_type(4)));
typedef float  f32x4  __attribute__((ext_vector_type(4)));

constexpr int Bc = 2, Nc = 2048, Dc = 1024, Hc = 16, DHc = 64;
constexpr int BN = Bc * Nc;     // 4096
constexpr int E3 = 3 * DHc;     // 192
constexpr int BH = Bc * Hc;     // 32
constexpr int NK = Hc * E3;     // 3072

__device__ __forceinline__ f32x4 mfma16(bf16x8 a, bf16x8 b, f32x4 c) {
  return __builtin_amdgcn_mfma_f32_16x16x32_bf16(a, b, c, 0, 0, 0);
}

__device__ __forceinline__ void gload16(const __bf16* g, __bf16* l) {
  __builtin_amdgcn_global_load_lds((const __attribute__((address_space(1))) void*)g,
                                   (__attribute__((address_space(3))) void*)l,
                                   16, 0, 0);
}

__device__ __forceinline__ float fexp2(float x) {
  return __builtin_amdgcn_exp2f(x);
}

// ---------- fused conversions (proven R18) ----------
constexpr int TP = 68;
__global__ __launch_bounds__(256) void cvt_all_kernel(
    const float* __restrict__ x,    __bf16* __restrict__ xb,
    const float* __restrict__ Wkqv, __bf16* __restrict__ wkt,
    const float* __restrict__ Wo,   __bf16* __restrict__ wot) {
  __shared__ __bf16 T[64][TP];
  const int blk = blockIdx.x;
  const int tid = threadIdx.x;
  if (blk < 4096) {
    int i = (blk * 256 + tid) * 4;
    float4 v = *(const float4*)(x + i);
    xb[i + 0] = (__bf16)v.x;
    xb[i + 1] = (__bf16)v.y;
    xb[i + 2] = (__bf16)v.z;
    xb[i + 3] = (__bf16)v.w;
    return;
  }
  const float* src;
  __bf16* dst;
  int R, C, c0, r0;
  size_t sbase;
  if (blk < 4096 + 768) {
    const int local = blk - 4096;
    R = Dc; C = E3;
    c0 = (local % 3) * 64;
    r0 = ((local / 3) & 15) * 64;
    sbase = (size_t)(local / 48) * R * C;
    src = Wkqv; dst = wkt;
  } else {
    const int local = blk - (4096 + 768);
    R = Dc; C = Dc;
    c0 = (local & 15) * 64;
    r0 = (local >> 4) * 64;
    sbase = 0;
    src = Wo; dst = wot;
  }
#pragma unroll
  for (int it = 0; it < 4; ++it) {
    int g = tid + it * 256;
    int r = g >> 4, c4 = (g & 15) * 4;
    float4 v = *(const float4*)&src[sbase + (size_t)(r0 + r) * C + c0 + c4];
    T[c4 + 0][r] = (__bf16)v.x;
    T[c4 + 1][r] = (__bf16)v.y;
    T[c4 + 2][r] = (__bf16)v.z;
    T[c4 + 3][r] = (__bf16)v.w;
  }
  __syncthreads();
#pragma unroll
  for (int it = 0; it < 2; ++it) {
    int g = tid + it * 256;
    int c = g >> 3, ch = (g & 7) * 8;
    bf16x4 u0 = *(const bf16x4*)&T[c][ch];
    bf16x4 u1 = *(const bf16x4*)&T[c][ch + 4];
    __bf16* dp = &dst[sbase + (size_t)(c0 + c) * R + r0 + ch];
    *(bf16x4*)dp = u0;
    *(bf16x4*)(dp + 4) = u1;
  }
}

// ---------- fused KQV projection GEMM: 128x192 head-aligned tiles (proven R14) ----------
__launch_bounds__(256)
__global__ void kqv_gemm_kernel(const __bf16* __restrict__ xb,
                                const __bf16* __restrict__ wkt,
                                const float* __restrict__ bkqv,
                                __bf16* __restrict__ kqv,
                                __bf16* __restrict__ vT) {
  const int mt = blockIdx.x;   // 0..31
  const int h  = blockIdx.y;   // 0..15 (head)
  __shared__ __align__(16) __bf16 Al[2][128][64];
  __shared__ __align__(16) __bf16 Bl[2][192][64];
  const int tid  = threadIdx.x;
  const int lane = tid & 63;
  const int w    = tid >> 6;
  const int fr   = lane & 15, fq = lane >> 4;
  const int fq4  = fq * 4;
  const int WR   = (w >> 1) * 64, WC = (w & 1) * 96;
  const int sr   = tid >> 3;
  const int sc8  = ((tid & 7) ^ (sr & 7)) * 8;
  const int wb   = (w << 3);
  const int m0   = mt * 128;
  const __bf16* wth = wkt + (size_t)h * E3 * Dc;

  auto STAGE = [&](int buf, int k0) {
#pragma unroll
    for (int j = 0; j < 4; ++j)
      gload16(&xb[(size_t)(m0 + j * 32 + sr) * Dc + k0 + sc8], &Al[buf][j * 32 + wb][0]);
#pragma unroll
    for (int j = 0; j < 6; ++j)
      gload16(&wth[(size_t)(j * 32 + sr) * Dc + k0 + sc8], &Bl[buf][j * 32 + wb][0]);
  };

  f32x4 acc[4][6] = {};
  STAGE(0, 0);
  int cur = 0;
  for (int t = 0; t < 16; ++t) {
    if (t < 15) {
      STAGE(cur ^ 1, (t + 1) * 64);
      asm volatile("s_waitcnt vmcnt(10)" ::: "memory");
    } else {
      asm volatile("s_waitcnt vmcnt(0)" ::: "memory");
    }
    asm volatile("s_barrier" ::: "memory");
    const char* Ab = (const char*)&Al[cur][0][0];
    const char* Bb = (const char*)&Bl[cur][0][0];
#pragma unroll
    for (int ks = 0; ks < 2; ++ks) {
      bf16x8 a_[4], b_[6];
#pragma unroll
      for (int mr = 0; mr < 4; ++mr) {
        int r = WR + mr * 16 + fr;
        a_[mr] = *(const bf16x8*)(Ab + r * 128 + ((ks * 64 + fq * 16) ^ ((r & 7) << 4)));
      }
#pragma unroll
      for (int nc = 0; nc < 6; ++nc) {
        int r = WC + nc * 16 + fr;
        b_[nc] = *(const bf16x8*)(Bb + r * 128 + ((ks * 64 + fq * 16) ^ ((r & 7) << 4)));
      }
#pragma unroll
      for (int mr = 0; mr < 4; ++mr)
#pragma unroll
        for (int nc = 0; nc < 6; ++nc)
          acc[mr][nc] = mfma16(a_[mr], b_[nc], acc[mr][nc]);
    }
    asm volatile("s_barrier" ::: "memory");
    cur ^= 1;
  }

  const int b = m0 >> 11;
#pragma unroll
  for (int nc = 0; nc < 6; ++nc) {
    const int eb = WC + nc * 16;
    const float bias = bkqv[h * E3 + eb + fr];
    if (eb < 64) {
      const float sc = 0.125f * 1.44269504088896f;
      const int el = eb + fr;
#pragma unroll
      for (int mr = 0; mr < 4; ++mr) {
        int nn0 = (m0 & (Nc - 1)) + WR + mr * 16 + fq4;
        bf16x4 v4;
#pragma unroll
        for (int i = 0; i < 4; ++i) v4[i] = (__bf16)((acc[mr][nc][i] + bias) * sc);
        *(bf16x4*)&kqv[((size_t)((b * Hc + h) * DHc + el)) * Nc + nn0] = v4;
      }
    } else if (eb < 128) {
      const int e = (eb - 64) + fr;
      __bf16* dst = kqv + (size_t)BH * Nc * DHc +
                    ((size_t)(b * Hc + h)) * Nc * DHc + e;
#pragma unroll
      for (int mr = 0; mr < 4; ++mr)
#pragma unroll
        for (int i = 0; i < 4; ++i) {
          int n = (m0 & (Nc - 1)) + WR + mr * 16 + fq4 + i;
          dst[(size_t)n * DHc] = (__bf16)(acc[mr][nc][i] + bias);
        }
    } else {
      const int el = eb - 128 + fr;
#pragma unroll
      for (int mr = 0; mr < 4; ++mr) {
        int nn0 = (m0 & (Nc - 1)) + WR + mr * 16 + fq4;
        bf16x4 v4;
#pragma unroll
        for (int i = 0; i < 4; ++i) v4[i] = (__bf16)(acc[mr][nc][i] + bias);
        *(bf16x4*)&vT[((size_t)((b * Hc + h) * DHc + el)) * Nc + nn0] = v4;
      }
    }
  }
}

// ---------- flash attention: lagged-PV pipeline (no mid-step lgkm drain) ----------
// Step t: QK_t || PV_{t-1}; softmax_t; write P_t; stage t+1; ONE barrier.
// K dbuf, V triple-buffer, P dbuf (per-wave private). No-max softmax (R9), hw-exp2.
__launch_bounds__(256)
__global__ void attn_kernel(const __bf16* __restrict__ kT,
                            const __bf16* __restrict__ qb,
                            const __bf16* __restrict__ vT,
                            __bf16* __restrict__ sab) {
  const int bx = blockIdx.x;   // 0..15
  const int by = blockIdx.y;   // 0..31
  const int bh   = 4 * (bx & 7) + (by >> 3);
  const int pair = (bx >> 3) * 8 + (by & 7);
  __shared__ __align__(16) __bf16 KqL[2][64][64];
  __shared__ __align__(16) __bf16 VtL[3][64][64];
  __shared__ __align__(16) __bf16 Pl[2][4][16][64];
  const int tid  = threadIdx.x;
  const int lane = tid & 63;
  const int w    = tid >> 6;
  const int fr   = lane & 15, fq = lane >> 4;
  const int fq4  = fq * 4;
  const int key  = (fr & 7) << 4;
  const int off0 = (fq * 16) ^ key;
  const int off1 = (fq * 16 + 64) ^ key;
  const __bf16* kth = kT + (size_t)bh * DHc * Nc;
  const __bf16* qbh = qb + (size_t)bh * Nc * DHc;
  const __bf16* vth = vT + (size_t)bh * DHc * Nc;
  const int b = bh >> 4, h = bh & 15;

  const int sch  = (tid & 7);
  const int r_s0 = tid >> 3;
  const int r_s1 = r_s0 + 32;
  const int swb0 = r_s0 * 128 + ((sch * 16) ^ ((r_s0 & 7) << 4));
  const int swb1 = r_s1 * 128 + ((sch * 16) ^ ((r_s1 & 7) << 4));

  for (int ph = 0; ph < 2; ++ph) {
    const int qt   = ph ? (31 - pair) : pair;
    const int n0   = qt * 64 + w * 16;
    const int ncol = n0 + fr;

    bf16x8 bq0, bq1;
#pragma unroll
    for (int j = 0; j < 8; ++j) {
      bq0[j] = kth[(size_t)(8 * fq + j) * Nc + n0 + fr];
      bq1[j] = kth[(size_t)(32 + 8 * fq + j) * Nc + n0 + fr];
    }

    float l_run = 0.f;
    f32x4 acc[4] = {};

    __syncthreads();   // prev phase's epilogue reads complete before restaging
    {
      bf16x8 k0a = *(const bf16x8*)&qbh[(size_t)r_s0 * DHc + sch * 8];
      bf16x8 k0b = *(const bf16x8*)&qbh[(size_t)r_s1 * DHc + sch * 8];
      bf16x8 v0a = *(const bf16x8*)&vth[(size_t)r_s0 * Nc + sch * 8];
      bf16x8 v0b = *(const bf16x8*)&vth[(size_t)r_s1 * Nc + sch * 8];
      *(bf16x8*)((char*)&KqL[0][0][0] + swb0) = k0a;
      *(bf16x8*)((char*)&KqL[0][0][0] + swb1) = k0b;
      *(bf16x8*)((char*)&VtL[0][0][0] + swb0) = v0a;
      *(bf16x8*)((char*)&VtL[0][0][0] + swb1) = v0b;
    }
    __syncthreads();

    int kcur = 0;
    for (int t = 0; t <= qt; ++t) {
      bf16x8 nk0, nk1, nv0, nv1;
      const bool more = (t < qt);
      if (more) {
        const int v1 = (t + 1) * 64;
        nk0 = *(const bf16x8*)&qbh[(size_t)(v1 + r_s0) * DHc + sch * 8];
        nk1 = *(const bf16x8*)&qbh[(size_t)(v1 + r_s1) * DHc + sch * 8];
        nv0 = *(const bf16x8*)&vth[(size_t)r_s0 * Nc + v1 + sch * 8];
        nv1 = *(const bf16x8*)&vth[(size_t)r_s1 * Nc + v1 + sch * 8];
      }

      const char* Kqb = (const char*)&KqL[kcur][0][0];

      // ---- QK_t
      f32x4 s[4];
      __builtin_amdgcn_s_setprio(1);
#pragma unroll
      for (int c = 0; c < 4; ++c) {
        const char* rp = Kqb + (c * 16 + fr) * 128;
        bf16x8 t0 = *(const bf16x8*)(rp + off0);
        bf16x8 t1 = *(const bf16x8*)(rp + off1);
        f32x4 z = {};
        z = mfma16(t0, bq0, z);
        z = mfma16(t1, bq1, z);
        s[c] = z;
      }
      // ---- PV_{t-1} (independent: P/V from previous step, barrier-drained)
      if (t > 0) {
        const char* Pp = (const char*)&Pl[(t - 1) & 1][w][0][0];
        const char* Vp = (const char*)&VtL[(t - 1) % 3][0][0];
        bf16x8 ap0 = *(const bf16x8*)(Pp + fr * 128 + off0);
        bf16x8 ap1 = *(const bf16x8*)(Pp + fr * 128 + off1);
#pragma unroll
        for (int d = 0; d < 4; ++d) {
          const char* vp = Vp + (d * 16 + fr) * 128;
          bf16x8 bv0 = *(const bf16x8*)(vp + off0);
          bf16x8 bv1 = *(const bf16x8*)(vp + off1);
          acc[d] = mfma16(ap0, bv0, acc[d]);
          acc[d] = mfma16(ap1, bv1, acc[d]);
        }
      }
      __builtin_amdgcn_s_setprio(0);

      // ---- softmax_t (no-max, exp2)
      if (t == qt) {
        const int thr = ncol - t * 64;
#pragma unroll
        for (int c = 0; c < 4; ++c)
#pragma unroll
          for (int i = 0; i < 4; ++i) {
            float pv = fexp2(s[c][i]);
            s[c][i] = (c * 16 + fq4 + i > thr) ? 0.f : pv;
          }
      } else {
#pragma unroll
        for (int c = 0; c < 4; ++c)
#pragma unroll
          for (int i = 0; i < 4; ++i) s[c][i] = fexp2(s[c][i]);
      }
      float cs0 = (s[0][0] + s[0][1]) + (s[0][2] + s[0][3]);
      float cs1 = (s[1][0] + s[1][1]) + (s[1][2] + s[1][3]);
      float cs2 = (s[2][0] + s[2][1]) + (s[2][2] + s[2][3]);
      float cs3 = (s[3][0] + s[3][1]) + (s[3][2] + s[3][3]);
      l_run += (cs0 + cs1) + (cs2 + cs3);

      // ---- write P_t (consumed next step, after the barrier)
      {
        char* Pc = (char*)&Pl[t & 1][w][0][0];
#pragma unroll
        for (int c = 0; c < 4; ++c) {
          bf16x4 p4;
#pragma unroll
          for (int i = 0; i < 4; ++i) p4[i] = (__bf16)s[c][i];
          *(bf16x4*)(Pc + fr * 128 + ((c * 32 + fq * 8) ^ key)) = p4;
        }
      }

      // ---- stage t+1 (K -> kcur^1, V -> (t+1)%3)
      if (more) {
        char* Kn = (char*)&KqL[kcur ^ 1][0][0];
        char* Vn = (char*)&VtL[(t + 1) % 3][0][0];
        *(bf16x8*)(Kn + swb0) = nk0;
        *(bf16x8*)(Kn + swb1) = nk1;
        *(bf16x8*)(Vn + swb0) = nv0;
        *(bf16x8*)(Vn + swb1) = nv1;
      }
      __syncthreads();
      kcur ^= 1;
    }

    // ---- epilogue: PV_qt
    {
      const char* Pp = (const char*)&Pl[qt & 1][w][0][0];
      const char* Vp = (const char*)&VtL[qt % 3][0][0];
      bf16x8 ap0 = *(const bf16x8*)(Pp + fr * 128 + off0);
      bf16x8 ap1 = *(const bf16x8*)(Pp + fr * 128 + off1);
      __builtin_amdgcn_s_setprio(1);
#pragma unroll
      for (int d = 0; d < 4; ++d) {
        const char* vp = Vp + (d * 16 + fr) * 128;
        bf16x8 bv0 = *(const bf16x8*)(vp + off0);
        bf16x8 bv1 = *(const bf16x8*)(vp + off1);
        acc[d] = mfma16(ap0, bv0, acc[d]);
        acc[d] = mfma16(ap1, bv1, acc[d]);
      }
      __builtin_amdgcn_s_setprio(0);
    }

    l_run += __shfl_xor(l_run, 16);
    l_run += __shfl_xor(l_run, 32);
    float linv[4];
#pragma unroll
    for (int ii = 0; ii < 4; ++ii) linv[ii] = 1.0f / __shfl(l_run, fq4 + ii);
#pragma unroll
    for (int d = 0; d < 4; ++d)
#pragma unroll
      for (int ii = 0; ii < 4; ++ii) {
        int n  = n0 + fq4 + ii;
        int dd = d * 16 + fr;
        sab[((size_t)(b * Nc + n)) * Dc + h * DHc + dd] = (__bf16)(acc[d][ii] * linv[ii]);
      }
  }
}

// ---------- output projection GEMM: 64x128 tiles, 2-phase dbuf (proven R17) ----------
__launch_bounds__(256)
__global__ void out_gemm_kernel(const __bf16* __restrict__ sab,
                                const __bf16* __restrict__ wot,
                                const float* __restrict__ bo,
                                float* __restrict__ out) {
  const int mt = blockIdx.x;   // 0..63
  const int nt = blockIdx.y;   // 0..7
  __shared__ __align__(16) __bf16 Al[2][64][64];
  __shared__ __align__(16) __bf16 Bl[2][128][64];
  const int tid  = threadIdx.x;
  const int lane = tid & 63;
  const int w    = tid >> 6;
  const int fr   = lane & 15, fq = lane >> 4;
  const int fq4  = fq * 4;
  const int WR   = (w >> 1) * 32, WC = (w & 1) * 64;
  const int sr   = tid >> 3;
  const int sc8  = ((tid & 7) ^ (sr & 7)) * 8;
  const int wb   = (w << 3);
  const int m0   = mt * 64, n0 = nt * 128;

  auto STAGE = [&](int buf, int k0) {
#pragma unroll
    for (int j = 0; j < 2; ++j)
      gload16(&sab[(size_t)(m0 + j * 32 + sr) * Dc + k0 + sc8], &Al[buf][j * 32 + wb][0]);
#pragma unroll
    for (int j = 0; j < 4; ++j)
      gload16(&wot[(size_t)(n0 + j * 32 + sr) * Dc + k0 + sc8], &Bl[buf][j * 32 + wb][0]);
  };

  f32x4 acc[2][4] = {};
  STAGE(0, 0);
  int cur = 0;
  for (int t = 0; t < 16; ++t) {
    if (t < 15) {
      STAGE(cur ^ 1, (t + 1) * 64);
      asm volatile("s_waitcnt vmcnt(6)" ::: "memory");
    } else {
      asm volatile("s_waitcnt vmcnt(0)" ::: "memory");
    }
    asm volatile("s_barrier" ::: "memory");
    const char* Ab = (const char*)&Al[cur][0][0];
    const char* Bb = (const char*)&Bl[cur][0][0];
#pragma unroll
    for (int ks = 0; ks < 2; ++ks) {
      bf16x8 a_[2], b_[4];
#pragma unroll
      for (int mr = 0; mr < 2; ++mr) {
        int r = WR + mr * 16 + fr;
        a_[mr] = *(const bf16x8*)(Ab + r * 128 + ((ks * 64 + fq * 16) ^ ((r & 7) << 4)));
      }
#pragma unroll
      for (int nc = 0; nc < 4; ++nc) {
        int r = WC + nc * 16 + fr;
        b_[nc] = *(const bf16x8*)(Bb + r * 128 + ((ks * 64 + fq * 16) ^ ((r & 7) << 4)));
      }
#pragma unroll
      for (int mr = 0; mr < 2; ++mr)
#pragma unroll
        for (int nc = 0; nc < 4; ++nc)
          acc[mr][nc] = mfma16(a_[mr], b_[nc], acc[mr][nc]);
    }
    asm volatile("s_barrier" ::: "memory");
    cur ^= 1;
  }
#pragma unroll
  for (int mr = 0; mr < 2; ++mr)
#pragma unroll
    for (int nc = 0; nc < 4; ++nc)
#pragma unroll
      for (int i = 0; i < 4; ++i) {
        int m = m0 + WR + mr * 16 + fq4 + i;
        int e = n0 + WC + nc * 16 + fr;
        out[(size_t)m * Dc + e] = acc[mr][nc][i] + bo[e];
      }
}

extern "C" void kernel_launch(void* const* d_in, const int* in_sizes, int n_in,
                              void* d_out, int out_size, void* d_ws, size_t ws_size,
                              hipStream_t stream) {
  const float* x    = (const float*)d_in[0];
  const float* Wkqv = (const float*)d_in[1];
  const float* bkqv = (const float*)d_in[2];
  const float* Wo   = (const float*)d_in[3];
  const float* bo   = (const float*)d_in[4];
  float* out = (float*)d_out;

  __bf16* xb   = (__bf16*)d_ws;
  __bf16* wkt  = xb  + (size_t)BN * Dc;
  __bf16* wot  = wkt + (size_t)NK * Dc;
  __bf16* kqv  = wot + (size_t)Dc * Dc;
  __bf16* kTb  = kqv;                                  // [32][64][2048] pre-scaled
  __bf16* qbuf = kqv + (size_t)BH * Nc * DHc;          // [32][2048][64]
  __bf16* vTb  = kqv + 2 * (size_t)BH * Nc * DHc;      // [32][64][2048]
  __bf16* sab  = kqv + 3 * (size_t)BH * Nc * DHc;

  cvt_all_kernel<<<4096 + 768 + 256, 256, 0, stream>>>(x, xb, Wkqv, wkt, Wo, wot);

  kqv_gemm_kernel<<<dim3(BN / 128, Hc), 256, 0, stream>>>(xb, wkt, bkqv, kqv, vTb);

  attn_kernel<<<dim3(16, BH), 256, 0, stream>>>(kTb, qbuf, vTb, sab);

  out_gemm_kernel<<<dim3(BN / 64, Dc / 128), 256, 0, stream>>>(sab, wot, bo, out);
}

// Round 20
// 94.036 us; speedup vs baseline: 1.0292x; 1.0292x over previous
//
#include <hip/hip_runtime.h>
#include <hip/hip_bf16.h>
#include <cstdint>
#include <cstddef>

typedef __bf16 bf16x8 __attribute__((ext_vector_type(8)));
typedef __bf16 bf16x4 __attribute__((ext_vector_type(4)));
typedef float  f32x4  __attribute__((ext_vector_type(4)));

constexpr int Bc = 2, Nc = 2048, Dc = 1024, Hc = 16, DHc = 64;
constexpr int BN = Bc * Nc;     // 4096
constexpr int E3 = 3 * DHc;     // 192
constexpr int BH = Bc * Hc;     // 32
constexpr int NK = Hc * E3;     // 3072

__device__ __forceinline__ f32x4 mfma16(bf16x8 a, bf16x8 b, f32x4 c) {
  return __builtin_amdgcn_mfma_f32_16x16x32_bf16(a, b, c, 0, 0, 0);
}

__device__ __forceinline__ void gload16(const __bf16* g, __bf16* l) {
  __builtin_amdgcn_global_load_lds((const __attribute__((address_space(1))) void*)g,
                                   (__attribute__((address_space(3))) void*)l,
                                   16, 0, 0);
}

__device__ __forceinline__ float fexp2(float x) {
  return __builtin_amdgcn_exp2f(x);
}

// ---------- fused conversions (proven R18) ----------
constexpr int TP = 68;
__global__ __launch_bounds__(256) void cvt_all_kernel(
    const float* __restrict__ x,    __bf16* __restrict__ xb,
    const float* __restrict__ Wkqv, __bf16* __restrict__ wkt,
    const float* __restrict__ Wo,   __bf16* __restrict__ wot) {
  __shared__ __bf16 T[64][TP];
  const int blk = blockIdx.x;
  const int tid = threadIdx.x;
  if (blk < 4096) {
    int i = (blk * 256 + tid) * 4;
    float4 v = *(const float4*)(x + i);
    xb[i + 0] = (__bf16)v.x;
    xb[i + 1] = (__bf16)v.y;
    xb[i + 2] = (__bf16)v.z;
    xb[i + 3] = (__bf16)v.w;
    return;
  }
  const float* src;
  __bf16* dst;
  int R, C, c0, r0;
  size_t sbase;
  if (blk < 4096 + 768) {
    const int local = blk - 4096;
    R = Dc; C = E3;
    c0 = (local % 3) * 64;
    r0 = ((local / 3) & 15) * 64;
    sbase = (size_t)(local / 48) * R * C;
    src = Wkqv; dst = wkt;
  } else {
    const int local = blk - (4096 + 768);
    R = Dc; C = Dc;
    c0 = (local & 15) * 64;
    r0 = (local >> 4) * 64;
    sbase = 0;
    src = Wo; dst = wot;
  }
#pragma unroll
  for (int it = 0; it < 4; ++it) {
    int g = tid + it * 256;
    int r = g >> 4, c4 = (g & 15) * 4;
    float4 v = *(const float4*)&src[sbase + (size_t)(r0 + r) * C + c0 + c4];
    T[c4 + 0][r] = (__bf16)v.x;
    T[c4 + 1][r] = (__bf16)v.y;
    T[c4 + 2][r] = (__bf16)v.z;
    T[c4 + 3][r] = (__bf16)v.w;
  }
  __syncthreads();
#pragma unroll
  for (int it = 0; it < 2; ++it) {
    int g = tid + it * 256;
    int c = g >> 3, ch = (g & 7) * 8;
    bf16x4 u0 = *(const bf16x4*)&T[c][ch];
    bf16x4 u1 = *(const bf16x4*)&T[c][ch + 4];
    __bf16* dp = &dst[sbase + (size_t)(c0 + c) * R + r0 + ch];
    *(bf16x4*)dp = u0;
    *(bf16x4*)(dp + 4) = u1;
  }
}

// ---------- fused KQV projection GEMM: 128x192 head-aligned tiles (proven R14) ----------
__launch_bounds__(256)
__global__ void kqv_gemm_kernel(const __bf16* __restrict__ xb,
                                const __bf16* __restrict__ wkt,
                                const float* __restrict__ bkqv,
                                __bf16* __restrict__ kqv,
                                __bf16* __restrict__ vT) {
  const int mt = blockIdx.x;   // 0..31
  const int h  = blockIdx.y;   // 0..15 (head)
  __shared__ __align__(16) __bf16 Al[2][128][64];
  __shared__ __align__(16) __bf16 Bl[2][192][64];
  const int tid  = threadIdx.x;
  const int lane = tid & 63;
  const int w    = tid >> 6;
  const int fr   = lane & 15, fq = lane >> 4;
  const int fq4  = fq * 4;
  const int WR   = (w >> 1) * 64, WC = (w & 1) * 96;
  const int sr   = tid >> 3;
  const int sc8  = ((tid & 7) ^ (sr & 7)) * 8;
  const int wb   = (w << 3);
  const int m0   = mt * 128;
  const __bf16* wth = wkt + (size_t)h * E3 * Dc;

  auto STAGE = [&](int buf, int k0) {
#pragma unroll
    for (int j = 0; j < 4; ++j)
      gload16(&xb[(size_t)(m0 + j * 32 + sr) * Dc + k0 + sc8], &Al[buf][j * 32 + wb][0]);
#pragma unroll
    for (int j = 0; j < 6; ++j)
      gload16(&wth[(size_t)(j * 32 + sr) * Dc + k0 + sc8], &Bl[buf][j * 32 + wb][0]);
  };

  f32x4 acc[4][6] = {};
  STAGE(0, 0);
  int cur = 0;
  for (int t = 0; t < 16; ++t) {
    if (t < 15) {
      STAGE(cur ^ 1, (t + 1) * 64);
      asm volatile("s_waitcnt vmcnt(10)" ::: "memory");
    } else {
      asm volatile("s_waitcnt vmcnt(0)" ::: "memory");
    }
    asm volatile("s_barrier" ::: "memory");
    const char* Ab = (const char*)&Al[cur][0][0];
    const char* Bb = (const char*)&Bl[cur][0][0];
#pragma unroll
    for (int ks = 0; ks < 2; ++ks) {
      bf16x8 a_[4], b_[6];
#pragma unroll
      for (int mr = 0; mr < 4; ++mr) {
        int r = WR + mr * 16 + fr;
        a_[mr] = *(const bf16x8*)(Ab + r * 128 + ((ks * 64 + fq * 16) ^ ((r & 7) << 4)));
      }
#pragma unroll
      for (int nc = 0; nc < 6; ++nc) {
        int r = WC + nc * 16 + fr;
        b_[nc] = *(const bf16x8*)(Bb + r * 128 + ((ks * 64 + fq * 16) ^ ((r & 7) << 4)));
      }
#pragma unroll
      for (int mr = 0; mr < 4; ++mr)
#pragma unroll
        for (int nc = 0; nc < 6; ++nc)
          acc[mr][nc] = mfma16(a_[mr], b_[nc], acc[mr][nc]);
    }
    asm volatile("s_barrier" ::: "memory");
    cur ^= 1;
  }

  const int b = m0 >> 11;
#pragma unroll
  for (int nc = 0; nc < 6; ++nc) {
    const int eb = WC + nc * 16;
    const float bias = bkqv[h * E3 + eb + fr];
    if (eb < 64) {
      const float sc = 0.125f * 1.44269504088896f;
      const int el = eb + fr;
#pragma unroll
      for (int mr = 0; mr < 4; ++mr) {
        int nn0 = (m0 & (Nc - 1)) + WR + mr * 16 + fq4;
        bf16x4 v4;
#pragma unroll
        for (int i = 0; i < 4; ++i) v4[i] = (__bf16)((acc[mr][nc][i] + bias) * sc);
        *(bf16x4*)&kqv[((size_t)((b * Hc + h) * DHc + el)) * Nc + nn0] = v4;
      }
    } else if (eb < 128) {
      const int e = (eb - 64) + fr;
      __bf16* dst = kqv + (size_t)BH * Nc * DHc +
                    ((size_t)(b * Hc + h)) * Nc * DHc + e;
#pragma unroll
      for (int mr = 0; mr < 4; ++mr)
#pragma unroll
        for (int i = 0; i < 4; ++i) {
          int n = (m0 & (Nc - 1)) + WR + mr * 16 + fq4 + i;
          dst[(size_t)n * DHc] = (__bf16)(acc[mr][nc][i] + bias);
        }
    } else {
      const int el = eb - 128 + fr;
#pragma unroll
      for (int mr = 0; mr < 4; ++mr) {
        int nn0 = (m0 & (Nc - 1)) + WR + mr * 16 + fq4;
        bf16x4 v4;
#pragma unroll
        for (int i = 0; i < 4; ++i) v4[i] = (__bf16)(acc[mr][nc][i] + bias);
        *(bf16x4*)&vT[((size_t)((b * Hc + h) * DHc + el)) * Nc + nn0] = v4;
      }
    }
  }
}

// ---------- flash attention: R14 proven (reg-staged dbuf, hw-exp2, no-max) ----------
__launch_bounds__(256)
__global__ void attn_kernel(const __bf16* __restrict__ kT,
                            const __bf16* __restrict__ qb,
                            const __bf16* __restrict__ vT,
                            __bf16* __restrict__ sab) {
  const int bx = blockIdx.x;   // 0..15
  const int by = blockIdx.y;   // 0..31
  const int bh   = 4 * (bx & 7) + (by >> 3);
  const int pair = (bx >> 3) * 8 + (by & 7);
  __shared__ __align__(16) __bf16 KqL[2][64][64];
  __shared__ __align__(16) __bf16 VtL[2][64][64];
  __shared__ __align__(16) __bf16 Pl[4][16][64];
  const int tid  = threadIdx.x;
  const int lane = tid & 63;
  const int w    = tid >> 6;
  const int fr   = lane & 15, fq = lane >> 4;
  const int fq4  = fq * 4;
  const int key  = (fr & 7) << 4;
  const int off0 = (fq * 16) ^ key;
  const int off1 = (fq * 16 + 64) ^ key;
  const __bf16* kth = kT + (size_t)bh * DHc * Nc;
  const __bf16* qbh = qb + (size_t)bh * Nc * DHc;
  const __bf16* vth = vT + (size_t)bh * DHc * Nc;
  const int b = bh >> 4, h = bh & 15;
  char* Pw = (char*)&Pl[w][0][0];

  const int sch  = (tid & 7);
  const int r_s0 = tid >> 3;
  const int r_s1 = r_s0 + 32;
  const int swb0 = r_s0 * 128 + ((sch * 16) ^ ((r_s0 & 7) << 4));
  const int swb1 = r_s1 * 128 + ((sch * 16) ^ ((r_s1 & 7) << 4));

  for (int ph = 0; ph < 2; ++ph) {
    const int qt   = ph ? (31 - pair) : pair;
    const int n0   = qt * 64 + w * 16;
    const int ncol = n0 + fr;

    bf16x8 bq0, bq1;
#pragma unroll
    for (int j = 0; j < 8; ++j) {
      bq0[j] = kth[(size_t)(8 * fq + j) * Nc + n0 + fr];
      bq1[j] = kth[(size_t)(32 + 8 * fq + j) * Nc + n0 + fr];
    }

    float l_run = 0.f;
    f32x4 acc[4] = {};

    __syncthreads();
    {
      bf16x8 k0a = *(const bf16x8*)&qbh[(size_t)r_s0 * DHc + sch * 8];
      bf16x8 k0b = *(const bf16x8*)&qbh[(size_t)r_s1 * DHc + sch * 8];
      bf16x8 v0a = *(const bf16x8*)&vth[(size_t)r_s0 * Nc + sch * 8];
      bf16x8 v0b = *(const bf16x8*)&vth[(size_t)r_s1 * Nc + sch * 8];
      *(bf16x8*)((char*)&KqL[0][0][0] + swb0) = k0a;
      *(bf16x8*)((char*)&KqL[0][0][0] + swb1) = k0b;
      *(bf16x8*)((char*)&VtL[0][0][0] + swb0) = v0a;
      *(bf16x8*)((char*)&VtL[0][0][0] + swb1) = v0b;
    }
    __syncthreads();

    int cur = 0;
    for (int t = 0; t <= qt; ++t) {
      bf16x8 nk0, nk1, nv0, nv1;
      const bool more = (t < qt);
      if (more) {
        const int v1 = (t + 1) * 64;
        nk0 = *(const bf16x8*)&qbh[(size_t)(v1 + r_s0) * DHc + sch * 8];
        nk1 = *(const bf16x8*)&qbh[(size_t)(v1 + r_s1) * DHc + sch * 8];
        nv0 = *(const bf16x8*)&vth[(size_t)r_s0 * Nc + v1 + sch * 8];
        nv1 = *(const bf16x8*)&vth[(size_t)r_s1 * Nc + v1 + sch * 8];
      }

      const char* Kqb = (const char*)&KqL[cur][0][0];
      const char* Vtb = (const char*)&VtL[cur][0][0];

      f32x4 s[4];
      __builtin_amdgcn_s_setprio(1);
#pragma unroll
      for (int c = 0; c < 4; ++c) {
        const char* rp = Kqb + (c * 16 + fr) * 128;
        bf16x8 t0 = *(const bf16x8*)(rp + off0);
        bf16x8 t1 = *(const bf16x8*)(rp + off1);
        f32x4 z = {};
        z = mfma16(t0, bq0, z);
        z = mfma16(t1, bq1, z);
        s[c] = z;
      }
      __builtin_amdgcn_s_setprio(0);

      if (t == qt) {
        const int thr = ncol - t * 64;
#pragma unroll
        for (int c = 0; c < 4; ++c)
#pragma unroll
          for (int i = 0; i < 4; ++i) {
            float pv = fexp2(s[c][i]);
            s[c][i] = (c * 16 + fq4 + i > thr) ? 0.f : pv;
          }
      } else {
#pragma unroll
        for (int c = 0; c < 4; ++c)
#pragma unroll
          for (int i = 0; i < 4; ++i) s[c][i] = fexp2(s[c][i]);
      }
      float cs0 = (s[0][0] + s[0][1]) + (s[0][2] + s[0][3]);
      float cs1 = (s[1][0] + s[1][1]) + (s[1][2] + s[1][3]);
      float cs2 = (s[2][0] + s[2][1]) + (s[2][2] + s[2][3]);
      float cs3 = (s[3][0] + s[3][1]) + (s[3][2] + s[3][3]);
      l_run += (cs0 + cs1) + (cs2 + cs3);

#pragma unroll
      for (int c = 0; c < 4; ++c) {
        bf16x4 p4;
#pragma unroll
        for (int i = 0; i < 4; ++i) p4[i] = (__bf16)s[c][i];
        *(bf16x4*)(Pw + fr * 128 + ((c * 32 + fq * 8) ^ key)) = p4;
      }
      asm volatile("s_waitcnt lgkmcnt(0)" ::: "memory");
      __builtin_amdgcn_sched_barrier(0);

      __builtin_amdgcn_s_setprio(1);
      bf16x8 ap0 = *(const bf16x8*)(Pw + fr * 128 + off0);
      bf16x8 ap1 = *(const bf16x8*)(Pw + fr * 128 + off1);
#pragma unroll
      for (int d = 0; d < 4; ++d) {
        const char* vp = Vtb + (d * 16 + fr) * 128;
        bf16x8 bv0 = *(const bf16x8*)(vp + off0);
        bf16x8 bv1 = *(const bf16x8*)(vp + off1);
        acc[d] = mfma16(ap0, bv0, acc[d]);
        acc[d] = mfma16(ap1, bv1, acc[d]);
      }
      __builtin_amdgcn_s_setprio(0);

      if (more) {
        char* Kn = (char*)&KqL[cur ^ 1][0][0];
        char* Vn = (char*)&VtL[cur ^ 1][0][0];
        *(bf16x8*)(Kn + swb0) = nk0;
        *(bf16x8*)(Kn + swb1) = nk1;
        *(bf16x8*)(Vn + swb0) = nv0;
        *(bf16x8*)(Vn + swb1) = nv1;
      }
      __syncthreads();
      cur ^= 1;
    }

    l_run += __shfl_xor(l_run, 16);
    l_run += __shfl_xor(l_run, 32);
    float linv[4];
#pragma unroll
    for (int ii = 0; ii < 4; ++ii) linv[ii] = 1.0f / __shfl(l_run, fq4 + ii);
#pragma unroll
    for (int d = 0; d < 4; ++d)
#pragma unroll
      for (int ii = 0; ii < 4; ++ii) {
        int n  = n0 + fq4 + ii;
        int dd = d * 16 + fr;
        sab[((size_t)(b * Nc + n)) * Dc + h * DHc + dd] = (__bf16)(acc[d][ii] * linv[ii]);
      }
  }
}

// ---------- output projection GEMM: 64x128 tiles, 2-phase dbuf (proven R17) ----------
__launch_bounds__(256)
__global__ void out_gemm_kernel(const __bf16* __restrict__ sab,
                                const __bf16* __restrict__ wot,
                                const float* __restrict__ bo,
                                float* __restrict__ out) {
  const int mt = blockIdx.x;   // 0..63
  const int nt = blockIdx.y;   // 0..7
  __shared__ __align__(16) __bf16 Al[2][64][64];
  __shared__ __align__(16) __bf16 Bl[2][128][64];
  const int tid  = threadIdx.x;
  const int lane = tid & 63;
  const int w    = tid >> 6;
  const int fr   = lane & 15, fq = lane >> 4;
  const int fq4  = fq * 4;
  const int WR   = (w >> 1) * 32, WC = (w & 1) * 64;
  const int sr   = tid >> 3;
  const int sc8  = ((tid & 7) ^ (sr & 7)) * 8;
  const int wb   = (w << 3);
  const int m0   = mt * 64, n0 = nt * 128;

  auto STAGE = [&](int buf, int k0) {
#pragma unroll
    for (int j = 0; j < 2; ++j)
      gload16(&sab[(size_t)(m0 + j * 32 + sr) * Dc + k0 + sc8], &Al[buf][j * 32 + wb][0]);
#pragma unroll
    for (int j = 0; j < 4; ++j)
      gload16(&wot[(size_t)(n0 + j * 32 + sr) * Dc + k0 + sc8], &Bl[buf][j * 32 + wb][0]);
  };

  f32x4 acc[2][4] = {};
  STAGE(0, 0);
  int cur = 0;
  for (int t = 0; t < 16; ++t) {
    if (t < 15) {
      STAGE(cur ^ 1, (t + 1) * 64);
      asm volatile("s_waitcnt vmcnt(6)" ::: "memory");
    } else {
      asm volatile("s_waitcnt vmcnt(0)" ::: "memory");
    }
    asm volatile("s_barrier" ::: "memory");
    const char* Ab = (const char*)&Al[cur][0][0];
    const char* Bb = (const char*)&Bl[cur][0][0];
#pragma unroll
    for (int ks = 0; ks < 2; ++ks) {
      bf16x8 a_[2], b_[4];
#pragma unroll
      for (int mr = 0; mr < 2; ++mr) {
        int r = WR + mr * 16 + fr;
        a_[mr] = *(const bf16x8*)(Ab + r * 128 + ((ks * 64 + fq * 16) ^ ((r & 7) << 4)));
      }
#pragma unroll
      for (int nc = 0; nc < 4; ++nc) {
        int r = WC + nc * 16 + fr;
        b_[nc] = *(const bf16x8*)(Bb + r * 128 + ((ks * 64 + fq * 16) ^ ((r & 7) << 4)));
      }
#pragma unroll
      for (int mr = 0; mr < 2; ++mr)
#pragma unroll
        for (int nc = 0; nc < 4; ++nc)
          acc[mr][nc] = mfma16(a_[mr], b_[nc], acc[mr][nc]);
    }
    asm volatile("s_barrier" ::: "memory");
    cur ^= 1;
  }
#pragma unroll
  for (int mr = 0; mr < 2; ++mr)
#pragma unroll
    for (int nc = 0; nc < 4; ++nc)
#pragma unroll
      for (int i = 0; i < 4; ++i) {
        int m = m0 + WR + mr * 16 + fq4 + i;
        int e = n0 + WC + nc * 16 + fr;
        out[(size_t)m * Dc + e] = acc[mr][nc][i] + bo[e];
      }
}

extern "C" void kernel_launch(void* const* d_in, const int* in_sizes, int n_in,
                              void* d_out, int out_size, void* d_ws, size_t ws_size,
                              hipStream_t stream) {
  const float* x    = (const float*)d_in[0];
  const float* Wkqv = (const float*)d_in[1];
  const float* bkqv = (const float*)d_in[2];
  const float* Wo   = (const float*)d_in[3];
  const float* bo   = (const float*)d_in[4];
  float* out = (float*)d_out;

  __bf16* xb   = (__bf16*)d_ws;
  __bf16* wkt  = xb  + (size_t)BN * Dc;
  __bf16* wot  = wkt + (size_t)NK * Dc;
  __bf16* kqv  = wot + (size_t)Dc * Dc;
  __bf16* kTb  = kqv;                                  // [32][64][2048] pre-scaled
  __bf16* qbuf = kqv + (size_t)BH * Nc * DHc;          // [32][2048][64]
  __bf16* vTb  = kqv + 2 * (size_t)BH * Nc * DHc;      // [32][64][2048]
  __bf16* sab  = kqv + 3 * (size_t)BH * Nc * DHc;

  cvt_all_kernel<<<4096 + 768 + 256, 256, 0, stream>>>(x, xb, Wkqv, wkt, Wo, wot);

  kqv_gemm_kernel<<<dim3(BN / 128, Hc), 256, 0, stream>>>(xb, wkt, bkqv, kqv, vTb);

  attn_kernel<<<dim3(16, BH), 256, 0, stream>>>(kTb, qbuf, vTb, sab);

  out_gemm_kernel<<<dim3(BN / 64, Dc / 128), 256, 0, stream>>>(sab, wot, bo, out);
}